// Round 10
// baseline (231.024 us; speedup 1.0000x reference)
//
#include <hip/hip_runtime.h>

#define LQ 768
#define DIN 256
#define DB 128
#define NH 8
#define DH 32

// ws float offsets
#define OFF_QB 0
#define OFF_KT (LQ*DIN)          // kT[DIN][LQ]  transposed, pre-scaled K
#define OFF_VB (2*LQ*DIN)
#define OFF_GB (3*LQ*DIN)
#define OFF_W2 (4*LQ*DIN)
#define OFF_SC (OFF_W2 + DB*NH)

// ---------------------------------------------------------------------------
// K1: proj (blocks 0..191, 4 rows each; K written transposed+scaled) +
//     setup (block 192: W2/S/C fold of the bias layernorm).
// ---------------------------------------------------------------------------
__global__ __launch_bounds__(256) void projsetup_kernel(
    const float* __restrict__ x, const float* __restrict__ lnw, const float* __restrict__ lnb,
    const float* __restrict__ Wq, const float* __restrict__ Wk, const float* __restrict__ Wv,
    const float* __restrict__ Wg, const float* __restrict__ bg,
    const float* __restrict__ lbw, const float* __restrict__ lbb, const float* __restrict__ Wb,
    float* __restrict__ qb, float* __restrict__ kT, float* __restrict__ vb, float* __restrict__ gb,
    float* __restrict__ W2, float* __restrict__ SC)
{
    const int tid = threadIdx.x;

    if (blockIdx.x == 192) {            // ---- setup ----
        if (tid < 128) {
            const int d = tid, lane = d & 63, wv = d >> 6;
            float w = lbw[d], b = lbb[d];
            float pS[NH], pC[NH];
            #pragma unroll
            for (int h = 0; h < NH; h++) {
                float wb = Wb[d*NH + h];
                float w2 = w * wb;
                W2[d*NH + h] = w2;
                pS[h] = w2;
                pC[h] = b * wb;
            }
            #pragma unroll
            for (int m = 1; m <= 32; m <<= 1) {
                #pragma unroll
                for (int h = 0; h < NH; h++) { pS[h] += __shfl_xor(pS[h], m); pC[h] += __shfl_xor(pC[h], m); }
            }
            __shared__ float red[2][16];
            if (lane == 0) {
                #pragma unroll
                for (int h = 0; h < NH; h++) { red[wv][h] = pS[h]; red[wv][NH+h] = pC[h]; }
            }
            __syncthreads();
            if (d < 16) SC[d] = red[0][d] + red[1][d];
        }
        return;
    }

    // ---- proj: 4 rows per block ----
    const int lane = tid & 63, rr = tid >> 6;
    const int row = blockIdx.x * 4 + rr;
    __shared__ float xn[4][DIN];

    float4 xv = ((const float4*)x)[row * (DIN/4) + lane];
    float s  = xv.x + xv.y + xv.z + xv.w;
    float ss = xv.x*xv.x + xv.y*xv.y + xv.z*xv.z + xv.w*xv.w;
    #pragma unroll
    for (int m = 1; m <= 32; m <<= 1) { s += __shfl_xor(s, m); ss += __shfl_xor(ss, m); }
    float mu  = s * (1.0f/DIN);
    float inv = rsqrtf(ss * (1.0f/DIN) - mu*mu + 1e-5f);
    float4 wv4 = ((const float4*)lnw)[lane];
    float4 bv4 = ((const float4*)lnb)[lane];
    float4 r4;
    r4.x = (xv.x - mu)*inv*wv4.x + bv4.x;
    r4.y = (xv.y - mu)*inv*wv4.y + bv4.y;
    r4.z = (xv.z - mu)*inv*wv4.z + bv4.z;
    r4.w = (xv.w - mu)*inv*wv4.w + bv4.w;
    *((float4*)&xn[rr][lane*4]) = r4;
    __syncthreads();

    const int col = tid;
    float aq[4] = {0,0,0,0}, ak[4] = {0,0,0,0}, av[4] = {0,0,0,0}, ag[4] = {0,0,0,0};
    for (int i4 = 0; i4 < DIN/4; i4++) {
        float4 x0 = *((const float4*)&xn[0][i4*4]);
        float4 x1 = *((const float4*)&xn[1][i4*4]);
        float4 x2 = *((const float4*)&xn[2][i4*4]);
        float4 x3 = *((const float4*)&xn[3][i4*4]);
        const float* p0 = (const float*)&x0;
        const float* p1 = (const float*)&x1;
        const float* p2 = (const float*)&x2;
        const float* p3 = (const float*)&x3;
        #pragma unroll
        for (int e = 0; e < 4; e++) {
            const int i = i4*4 + e;
            float wq = Wq[i*DIN + col], wk = Wk[i*DIN + col];
            float wvv = Wv[i*DIN + col], wg = Wg[i*DIN + col];
            aq[0] = fmaf(p0[e], wq, aq[0]); aq[1] = fmaf(p1[e], wq, aq[1]);
            aq[2] = fmaf(p2[e], wq, aq[2]); aq[3] = fmaf(p3[e], wq, aq[3]);
            ak[0] = fmaf(p0[e], wk, ak[0]); ak[1] = fmaf(p1[e], wk, ak[1]);
            ak[2] = fmaf(p2[e], wk, ak[2]); ak[3] = fmaf(p3[e], wk, ak[3]);
            av[0] = fmaf(p0[e], wvv, av[0]); av[1] = fmaf(p1[e], wvv, av[1]);
            av[2] = fmaf(p2[e], wvv, av[2]); av[3] = fmaf(p3[e], wvv, av[3]);
            ag[0] = fmaf(p0[e], wg, ag[0]); ag[1] = fmaf(p1[e], wg, ag[1]);
            ag[2] = fmaf(p2[e], wg, ag[2]); ag[3] = fmaf(p3[e], wg, ag[3]);
        }
    }
    const float kscale = 0.17677669529663687f;  // 1/sqrt(DH)
    float bgv = bg[col];
    #pragma unroll
    for (int r = 0; r < 4; r++) {
        const int orow = blockIdx.x*4 + r;
        qb[orow*DIN + col] = aq[r];
        vb[orow*DIN + col] = av[r];
        gb[orow*DIN + col] = 1.0f/(1.0f + __expf(-(ag[r] + bgv)));
    }
    *((float4*)&kT[col*LQ + blockIdx.x*4]) =
        make_float4(ak[0]*kscale, ak[1]*kscale, ak[2]*kscale, ak[3]*kscale);
}

// ---------------------------------------------------------------------------
// K2: mega per-q kernel. 768 blocks x 256 threads (4 waves), 2 blocks/CU.
// R9 structure with ONE change: the staging pipeline is a ROLLED loop with
// intra-iteration v live range (issue t+1 -> scan t -> lgkm -> write t+1),
// so the staging registers cannot spill to scratch (R9: 192 MB of phantom
// scratch writes from the fully-unrolled rotation).
// ---------------------------------------------------------------------------
__global__ __launch_bounds__(256, 2) void mega_kernel(
    const float* __restrict__ bias, const float* __restrict__ W2g,
    const float* __restrict__ SCg, const float* __restrict__ qbuf,
    const float* __restrict__ kT, const float* __restrict__ vbuf,
    const float* __restrict__ gbuf, const float* __restrict__ Wo,
    const float* __restrict__ bo, float* __restrict__ out)
{
    __shared__ float tiles[4][2048];    // 8KB per wave (single buffer)
    __shared__ float w2p[4*264];        // 4 q4-slabs, stride 264
    __shared__ float pT[NH][776];
    __shared__ float ao[DIN];
    __shared__ float isum[NH];

    const int tid  = threadIdx.x;
    const int q    = blockIdx.x;
    const int w    = tid >> 6;
    const int lane = tid & 63;
    const int key  = lane & 15;
    const int q4   = lane >> 4;

    const char* gwave = (const char*)bias + ((size_t)q*LQ + w*192) * (DB*4);
    float* tw = &tiles[w][0];

    // per-lane source offset with the involution swizzle (bits 4..7 ^= key)
    int soff[8];
    #pragma unroll
    for (int c = 0; c < 8; c++) {
        int L = c*1024 + lane*16;
        soff[c] = L ^ (((L >> 9) & 15) << 4);
    }

    float4 v[8];
    // issue tile 0 loads (fly during w2p fill + qk)
    #pragma unroll
    for (int c = 0; c < 8; c++) v[c] = *(const float4*)(gwave + soff[c]);

    // w2p fill
    for (int j = tid; j < 4*264; j += 256) {
        int g = j / 264, rem = j - g*264;
        w2p[j] = (rem < 256) ? W2g[g*256 + rem] : 0.0f;
    }

    // qk prologue: 192 threads, 4 keys each, all 8 heads -> pT
    if (tid < 192) {
        float acc[4][NH];
        #pragma unroll
        for (int e = 0; e < 4; e++)
            #pragma unroll
            for (int h = 0; h < NH; h++) acc[e][h] = 0.f;
        const float* qp = qbuf + (size_t)q*DIN;          // uniform -> s_load
        #pragma unroll
        for (int h = 0; h < NH; h++) {
            #pragma unroll
            for (int dd = 0; dd < DH; dd++) {
                const int d = h*DH + dd;
                float4 kv = *(const float4*)(kT + (size_t)d*LQ + tid*4);
                float qa = qp[d];
                acc[0][h] = fmaf(qa, kv.x, acc[0][h]);
                acc[1][h] = fmaf(qa, kv.y, acc[1][h]);
                acc[2][h] = fmaf(qa, kv.z, acc[2][h]);
                acc[3][h] = fmaf(qa, kv.w, acc[3][h]);
            }
        }
        #pragma unroll
        for (int h = 0; h < NH; h++)
            *(float4*)&pT[h][tid*4] = make_float4(acc[0][h], acc[1][h], acc[2][h], acc[3][h]);
    }

    asm volatile("s_waitcnt lgkmcnt(0)" ::: "memory");
    __builtin_amdgcn_s_barrier();
    asm volatile("" ::: "memory");

    float Sh[NH], Ch[NH];
    #pragma unroll
    for (int h = 0; h < NH; h++) { Sh[h] = SCg[h]; Ch[h] = SCg[NH + h]; }

    // write tile0 (auto-waits v's vmcnt)
    #pragma unroll
    for (int c = 0; c < 8; c++) *(float4*)((char*)tw + c*1024 + lane*16) = v[c];

    const int rbase0 = ((key << 9) | (q4 << 7)) ^ (key << 4);
    const float* wp = &w2p[q4*264];

    #pragma unroll 1
    for (int t = 0; t < 12; t++) {
        // ---- issue loads for tile t+1 (in flight across the scan below) ----
        if (t < 11) {
            const char* gs = gwave + (size_t)(t + 1)*8192;
            #pragma unroll
            for (int c = 0; c < 8; c++) v[c] = *(const float4*)(gs + soff[c]);
        }
        asm volatile("" ::: "memory");   // loads stay above the scan

        // ---- scan tile t ----
        float s = 0.f, ss = 0.f;
        float acc[NH] = {0,0,0,0,0,0,0,0};
        #pragma unroll
        for (int j = 0; j < 8; j++) {
            float4 bv = *(const float4*)((const char*)tw + (rbase0 ^ (j << 4)));
            const float* wj = wp + j*32;
            #pragma unroll
            for (int e = 0; e < 4; e++) {
                float xv = (&bv.x)[e];
                s += xv; ss = fmaf(xv, xv, ss);
                float4 w0 = *(const float4*)(wj + e*8);
                float4 w1 = *(const float4*)(wj + e*8 + 4);
                acc[0] = fmaf(xv, w0.x, acc[0]); acc[1] = fmaf(xv, w0.y, acc[1]);
                acc[2] = fmaf(xv, w0.z, acc[2]); acc[3] = fmaf(xv, w0.w, acc[3]);
                acc[4] = fmaf(xv, w1.x, acc[4]); acc[5] = fmaf(xv, w1.y, acc[5]);
                acc[6] = fmaf(xv, w1.z, acc[6]); acc[7] = fmaf(xv, w1.w, acc[7]);
            }
        }
        #pragma unroll
        for (int m = 16; m <= 32; m <<= 1) {
            s += __shfl_xor(s, m); ss += __shfl_xor(ss, m);
            #pragma unroll
            for (int h = 0; h < NH; h++) acc[h] += __shfl_xor(acc[h], m);
        }
        if (q4 == 0) {
            float mu  = s * (1.0f/DB);
            float inv = rsqrtf(ss * (1.0f/DB) - mu*mu + 1e-5f);
            const int k = w*192 + t*16 + key;
            #pragma unroll
            for (int h = 0; h < NH; h++)
                pT[h][k] += fmaf(inv, fmaf(-mu, Sh[h], acc[h]), Ch[h]);
        }

        // ---- scan's LDS reads done -> overwrite buffer with tile t+1 ----
        if (t < 11) {
            asm volatile("s_waitcnt lgkmcnt(0)" ::: "memory");
            #pragma unroll
            for (int c = 0; c < 8; c++) *(float4*)((char*)tw + c*1024 + lane*16) = v[c];
        }
    }

    asm volatile("s_waitcnt lgkmcnt(0)" ::: "memory");
    __builtin_amdgcn_s_barrier();
    asm volatile("" ::: "memory");

    // ---- softmax over keys per head ----
    {
        const int h = tid >> 5, l = tid & 31;
        float m = -1e30f;
        for (int i = l; i < LQ; i += 32) m = fmaxf(m, pT[h][i]);
        #pragma unroll
        for (int mm = 1; mm <= 16; mm <<= 1) m = fmaxf(m, __shfl_xor(m, mm));
        float sum = 0.f;
        for (int i = l; i < LQ; i += 32) {
            float e = __expf(pT[h][i] - m);
            pT[h][i] = e;
            sum += e;
        }
        #pragma unroll
        for (int mm = 1; mm <= 16; mm <<= 1) sum += __shfl_xor(sum, mm);
        if (l == 0) isum[h] = 1.0f / sum;
    }
    __syncthreads();

    // ---- PV + gate ----
    {
        const int h = tid >> 5, d = tid & 31;
        const float* vp = vbuf + h*DH + d;
        float a = 0.f;
        for (int k4 = 0; k4 < LQ/4; k4++) {
            float4 p = *(const float4*)&pT[h][k4*4];     // broadcast
            a = fmaf(p.x, vp[(size_t)(k4*4+0)*DIN], a);
            a = fmaf(p.y, vp[(size_t)(k4*4+1)*DIN], a);
            a = fmaf(p.z, vp[(size_t)(k4*4+2)*DIN], a);
            a = fmaf(p.w, vp[(size_t)(k4*4+3)*DIN], a);
        }
        ao[tid] = a * isum[h] * gbuf[(size_t)q*DIN + tid];
    }
    __syncthreads();

    // ---- output projection ----
    {
        float o = bo[tid];
        for (int i = 0; i < DIN; i++) o = fmaf(ao[i], Wo[i*DIN + tid], o);
        out[(size_t)q*DIN + tid] = o;
    }
}

extern "C" void kernel_launch(void* const* d_in, const int* in_sizes, int n_in,
                              void* d_out, int out_size, void* d_ws, size_t ws_size,
                              hipStream_t stream) {
    const float* x    = (const float*)d_in[0];
    const float* bias = (const float*)d_in[1];
    const float* lnw  = (const float*)d_in[2];
    const float* lnb  = (const float*)d_in[3];
    const float* lbw  = (const float*)d_in[4];
    const float* lbb  = (const float*)d_in[5];
    const float* Wq   = (const float*)d_in[6];
    const float* Wk   = (const float*)d_in[7];
    const float* Wv   = (const float*)d_in[8];
    const float* Wb   = (const float*)d_in[9];
    const float* Wg   = (const float*)d_in[10];
    const float* bg   = (const float*)d_in[11];
    const float* Wo   = (const float*)d_in[12];
    const float* bo   = (const float*)d_in[13];

    float* ws = (float*)d_ws;
    float* qb = ws + OFF_QB;
    float* kT = ws + OFF_KT;
    float* vb = ws + OFF_VB;
    float* gb = ws + OFF_GB;
    float* W2 = ws + OFF_W2;
    float* SC = ws + OFF_SC;

    projsetup_kernel<<<193, 256, 0, stream>>>(x, lnw, lnb, Wq, Wk, Wv, Wg, bg,
                                              lbw, lbb, Wb, qb, kT, vb, gb, W2, SC);
    mega_kernel<<<LQ, 256, 0, stream>>>(bias, W2, SC, qb, kT, vb, gb, Wo, bo, (float*)d_out);
}

// Round 11
// 204.010 us; speedup vs baseline: 1.1324x; 1.1324x over previous
//
#include <hip/hip_runtime.h>

#define LQ 768
#define DIN 256
#define DB 128
#define NH 8
#define DH 32

// ws float offsets
#define OFF_QB 0
#define OFF_KT (LQ*DIN)          // kT[DIN][LQ]  transposed, pre-scaled K
#define OFF_VB (2*LQ*DIN)
#define OFF_GB (3*LQ*DIN)
#define OFF_W2 (4*LQ*DIN)
#define OFF_SC (OFF_W2 + DB*NH)

__device__ __forceinline__ void gload_lds16(const void* g, void* l) {
    __builtin_amdgcn_global_load_lds(
        (__attribute__((address_space(1))) const void*)g,
        (__attribute__((address_space(3))) void*)l,
        16, 0, 0);
}

// ---------------------------------------------------------------------------
// K1: proj (blocks 0..191, 4 rows each; K written transposed+scaled) +
//     setup (block 192: W2/S/C fold of the bias layernorm).
// ---------------------------------------------------------------------------
__global__ __launch_bounds__(256) void projsetup_kernel(
    const float* __restrict__ x, const float* __restrict__ lnw, const float* __restrict__ lnb,
    const float* __restrict__ Wq, const float* __restrict__ Wk, const float* __restrict__ Wv,
    const float* __restrict__ Wg, const float* __restrict__ bg,
    const float* __restrict__ lbw, const float* __restrict__ lbb, const float* __restrict__ Wb,
    float* __restrict__ qb, float* __restrict__ kT, float* __restrict__ vb, float* __restrict__ gb,
    float* __restrict__ W2, float* __restrict__ SC)
{
    const int tid = threadIdx.x;

    if (blockIdx.x == 192) {            // ---- setup ----
        if (tid < 128) {
            const int d = tid, lane = d & 63, wv = d >> 6;
            float w = lbw[d], b = lbb[d];
            float pS[NH], pC[NH];
            #pragma unroll
            for (int h = 0; h < NH; h++) {
                float wb = Wb[d*NH + h];
                float w2 = w * wb;
                W2[d*NH + h] = w2;
                pS[h] = w2;
                pC[h] = b * wb;
            }
            #pragma unroll
            for (int m = 1; m <= 32; m <<= 1) {
                #pragma unroll
                for (int h = 0; h < NH; h++) { pS[h] += __shfl_xor(pS[h], m); pC[h] += __shfl_xor(pC[h], m); }
            }
            __shared__ float red[2][16];
            if (lane == 0) {
                #pragma unroll
                for (int h = 0; h < NH; h++) { red[wv][h] = pS[h]; red[wv][NH+h] = pC[h]; }
            }
            __syncthreads();
            if (d < 16) SC[d] = red[0][d] + red[1][d];
        }
        return;
    }

    // ---- proj: 4 rows per block ----
    const int lane = tid & 63, rr = tid >> 6;
    const int row = blockIdx.x * 4 + rr;
    __shared__ float xn[4][DIN];

    float4 xv = ((const float4*)x)[row * (DIN/4) + lane];
    float s  = xv.x + xv.y + xv.z + xv.w;
    float ss = xv.x*xv.x + xv.y*xv.y + xv.z*xv.z + xv.w*xv.w;
    #pragma unroll
    for (int m = 1; m <= 32; m <<= 1) { s += __shfl_xor(s, m); ss += __shfl_xor(ss, m); }
    float mu  = s * (1.0f/DIN);
    float inv = rsqrtf(ss * (1.0f/DIN) - mu*mu + 1e-5f);
    float4 wv4 = ((const float4*)lnw)[lane];
    float4 bv4 = ((const float4*)lnb)[lane];
    float4 r4;
    r4.x = (xv.x - mu)*inv*wv4.x + bv4.x;
    r4.y = (xv.y - mu)*inv*wv4.y + bv4.y;
    r4.z = (xv.z - mu)*inv*wv4.z + bv4.z;
    r4.w = (xv.w - mu)*inv*wv4.w + bv4.w;
    *((float4*)&xn[rr][lane*4]) = r4;
    __syncthreads();

    const int col = tid;
    float aq[4] = {0,0,0,0}, ak[4] = {0,0,0,0}, av[4] = {0,0,0,0}, ag[4] = {0,0,0,0};
    for (int i4 = 0; i4 < DIN/4; i4++) {
        float4 x0 = *((const float4*)&xn[0][i4*4]);
        float4 x1 = *((const float4*)&xn[1][i4*4]);
        float4 x2 = *((const float4*)&xn[2][i4*4]);
        float4 x3 = *((const float4*)&xn[3][i4*4]);
        const float* p0 = (const float*)&x0;
        const float* p1 = (const float*)&x1;
        const float* p2 = (const float*)&x2;
        const float* p3 = (const float*)&x3;
        #pragma unroll
        for (int e = 0; e < 4; e++) {
            const int i = i4*4 + e;
            float wq = Wq[i*DIN + col], wk = Wk[i*DIN + col];
            float wvv = Wv[i*DIN + col], wg = Wg[i*DIN + col];
            aq[0] = fmaf(p0[e], wq, aq[0]); aq[1] = fmaf(p1[e], wq, aq[1]);
            aq[2] = fmaf(p2[e], wq, aq[2]); aq[3] = fmaf(p3[e], wq, aq[3]);
            ak[0] = fmaf(p0[e], wk, ak[0]); ak[1] = fmaf(p1[e], wk, ak[1]);
            ak[2] = fmaf(p2[e], wk, ak[2]); ak[3] = fmaf(p3[e], wk, ak[3]);
            av[0] = fmaf(p0[e], wvv, av[0]); av[1] = fmaf(p1[e], wvv, av[1]);
            av[2] = fmaf(p2[e], wvv, av[2]); av[3] = fmaf(p3[e], wvv, av[3]);
            ag[0] = fmaf(p0[e], wg, ag[0]); ag[1] = fmaf(p1[e], wg, ag[1]);
            ag[2] = fmaf(p2[e], wg, ag[2]); ag[3] = fmaf(p3[e], wg, ag[3]);
        }
    }
    const float kscale = 0.17677669529663687f;  // 1/sqrt(DH)
    float bgv = bg[col];
    #pragma unroll
    for (int r = 0; r < 4; r++) {
        const int orow = blockIdx.x*4 + r;
        qb[orow*DIN + col] = aq[r];
        vb[orow*DIN + col] = av[r];
        gb[orow*DIN + col] = 1.0f/(1.0f + __expf(-(ag[r] + bgv)));
    }
    *((float4*)&kT[col*LQ + blockIdx.x*4]) =
        make_float4(ak[0]*kscale, ak[1]*kscale, ak[2]*kscale, ak[3]*kscale);
}

// ---------------------------------------------------------------------------
// K2: mega per-q kernel, gload_lds edition. 768 blocks x 256 threads.
// Per wave: 192 keys = 24 tiles of 8 keys x 128 dims (4KB), double-buffered
// private LDS buffers, staged by 4x global_load_lds(16B) per tile with
// pre-swizzled global source (LDS dest linear; involution L ^= ((L>>9)&7)<<4).
// Steady-state s_waitcnt vmcnt(4): tile t retired, tile t+1 in flight.
// NO staging VGPRs -> nothing to spill (R9/R10: ~200 MB scratch writes).
// Scan lane = (key=lane&7, seg=lane>>3) over 16 dims; W2 slabs stride 136.
// ---------------------------------------------------------------------------
__global__ __launch_bounds__(256, 2) void mega_kernel(
    const float* __restrict__ bias, const float* __restrict__ W2g,
    const float* __restrict__ SCg, const float* __restrict__ qbuf,
    const float* __restrict__ kT, const float* __restrict__ vbuf,
    const float* __restrict__ gbuf, const float* __restrict__ Wo,
    const float* __restrict__ bo, float* __restrict__ out)
{
    __shared__ float tiles[4][2][1024];  // [wave][buf][4KB]
    __shared__ float w2p[8*136];         // 8 seg-slabs (16 dims x 8 heads), stride 136
    __shared__ float pT[NH][776];
    __shared__ float ao[DIN];
    __shared__ float isum[NH];

    const int tid  = threadIdx.x;
    const int q    = blockIdx.x;
    const int w    = tid >> 6;
    const int lane = tid & 63;
    const int key  = lane & 7;       // key within 8-key tile
    const int seg  = lane >> 3;      // 16-dim segment 0..7
    const int kw   = w * 192;

    const char* gwave = (const char*)bias + ((size_t)q*LQ + kw) * (DB*4);

    // stage tile t into buffer b: linear LDS dest, swizzled global src
    #define STAGE(t, b) {                                                    \
        const char* gt = gwave + (size_t)(t)*4096;                           \
        char* lb = (char*)&tiles[w][b][0];                                   \
        _Pragma("unroll")                                                    \
        for (int c = 0; c < 4; c++) {                                        \
            int L  = c*1024 + lane*16;                                       \
            int sw = L ^ (((L >> 9) & 7) << 4);                              \
            gload_lds16(gt + sw, lb + c*1024);                               \
        } }

    // prologue: stage tiles 0,1 (fly during w2p fill + qk below)
    STAGE(0, 0);
    STAGE(1, 1);

    // w2p fill: slab g holds W2 rows for dims g*16..+15 (128 floats, pad 8)
    for (int j = tid; j < 8*136; j += 256) {
        int g = j / 136, rem = j - g*136;
        w2p[j] = (rem < 128) ? W2g[g*128 + rem] : 0.0f;
    }

    // qk prologue: 192 threads, 4 keys each, all 8 heads -> pT
    if (tid < 192) {
        float acc[4][NH];
        #pragma unroll
        for (int e = 0; e < 4; e++)
            #pragma unroll
            for (int h = 0; h < NH; h++) acc[e][h] = 0.f;
        const float* qp = qbuf + (size_t)q*DIN;          // uniform -> s_load
        #pragma unroll
        for (int h = 0; h < NH; h++) {
            #pragma unroll
            for (int dd = 0; dd < DH; dd++) {
                const int d = h*DH + dd;
                float4 kv = *(const float4*)(kT + (size_t)d*LQ + tid*4);
                float qa = qp[d];
                acc[0][h] = fmaf(qa, kv.x, acc[0][h]);
                acc[1][h] = fmaf(qa, kv.y, acc[1][h]);
                acc[2][h] = fmaf(qa, kv.z, acc[2][h]);
                acc[3][h] = fmaf(qa, kv.w, acc[3][h]);
            }
        }
        #pragma unroll
        for (int h = 0; h < NH; h++)
            *(float4*)&pT[h][tid*4] = make_float4(acc[0][h], acc[1][h], acc[2][h], acc[3][h]);
    }

    asm volatile("s_waitcnt lgkmcnt(0)" ::: "memory");
    __builtin_amdgcn_s_barrier();

    float Sh[NH], Ch[NH];
    #pragma unroll
    for (int h = 0; h < NH; h++) { Sh[h] = SCg[h]; Ch[h] = SCg[NH + h]; }

    // scan read base: LDS[A] holds global byte A ^ ((A>>9)&7)<<4 (involution)
    const int rx = (key*512 + seg*64) ^ (key*16);
    const float* wp = &w2p[seg*136];

    #define SCAN(t) {                                                        \
        const char* tb = (const char*)&tiles[w][(t)&1][0];                   \
        float s = 0.f, ss = 0.f;                                             \
        float acc[NH] = {0,0,0,0,0,0,0,0};                                   \
        _Pragma("unroll")                                                    \
        for (int j = 0; j < 4; j++) {                                        \
            float4 bv = *(const float4*)(tb + (rx ^ (j << 4)));              \
            const float* wj = wp + j*32;                                     \
            _Pragma("unroll")                                                \
            for (int e = 0; e < 4; e++) {                                    \
                float xv = (&bv.x)[e];                                       \
                s += xv; ss = fmaf(xv, xv, ss);                              \
                float4 w0 = *(const float4*)(wj + e*8);                      \
                float4 w1 = *(const float4*)(wj + e*8 + 4);                  \
                acc[0] = fmaf(xv, w0.x, acc[0]); acc[1] = fmaf(xv, w0.y, acc[1]); \
                acc[2] = fmaf(xv, w0.z, acc[2]); acc[3] = fmaf(xv, w0.w, acc[3]); \
                acc[4] = fmaf(xv, w1.x, acc[4]); acc[5] = fmaf(xv, w1.y, acc[5]); \
                acc[6] = fmaf(xv, w1.z, acc[6]); acc[7] = fmaf(xv, w1.w, acc[7]); \
            }                                                                \
        }                                                                    \
        _Pragma("unroll")                                                    \
        for (int m = 8; m <= 32; m <<= 1) {                                  \
            s += __shfl_xor(s, m); ss += __shfl_xor(ss, m);                  \
            _Pragma("unroll")                                                \
            for (int h = 0; h < NH; h++) acc[h] += __shfl_xor(acc[h], m);    \
        }                                                                    \
        if (seg == 0) {                                                      \
            float mu  = s * (1.0f/DB);                                       \
            float inv = rsqrtf(ss * (1.0f/DB) - mu*mu + 1e-5f);              \
            const int k = kw + (t)*8 + key;                                  \
            _Pragma("unroll")                                                \
            for (int h = 0; h < NH; h++)                                     \
                pT[h][k] += fmaf(inv, fmaf(-mu, Sh[h], acc[h]), Ch[h]);      \
        } }

    #pragma unroll 1
    for (int t = 0; t < 22; t++) {
        asm volatile("s_waitcnt vmcnt(4)" ::: "memory");   // tile t landed
        SCAN(t);
        STAGE(t + 2, t & 1);                               // overwrite t's buffer
    }
    asm volatile("s_waitcnt vmcnt(4)" ::: "memory");
    SCAN(22);
    asm volatile("s_waitcnt vmcnt(0)" ::: "memory");
    SCAN(23);
    #undef SCAN
    #undef STAGE

    asm volatile("s_waitcnt lgkmcnt(0)" ::: "memory");
    __builtin_amdgcn_s_barrier();

    // ---- softmax over keys per head ----
    {
        const int h = tid >> 5, l = tid & 31;
        float m = -1e30f;
        for (int i = l; i < LQ; i += 32) m = fmaxf(m, pT[h][i]);
        #pragma unroll
        for (int mm = 1; mm <= 16; mm <<= 1) m = fmaxf(m, __shfl_xor(m, mm));
        float sum = 0.f;
        for (int i = l; i < LQ; i += 32) {
            float e = __expf(pT[h][i] - m);
            pT[h][i] = e;
            sum += e;
        }
        #pragma unroll
        for (int mm = 1; mm <= 16; mm <<= 1) sum += __shfl_xor(sum, mm);
        if (l == 0) isum[h] = 1.0f / sum;
    }
    __syncthreads();

    // ---- PV + gate ----
    {
        const int h = tid >> 5, d = tid & 31;
        const float* vp = vbuf + h*DH + d;
        float a = 0.f;
        for (int k4 = 0; k4 < LQ/4; k4++) {
            float4 p = *(const float4*)&pT[h][k4*4];     // broadcast
            a = fmaf(p.x, vp[(size_t)(k4*4+0)*DIN], a);
            a = fmaf(p.y, vp[(size_t)(k4*4+1)*DIN], a);
            a = fmaf(p.z, vp[(size_t)(k4*4+2)*DIN], a);
            a = fmaf(p.w, vp[(size_t)(k4*4+3)*DIN], a);
        }
        ao[tid] = a * isum[h] * gbuf[(size_t)q*DIN + tid];
    }
    __syncthreads();

    // ---- output projection ----
    {
        float o = bo[tid];
        for (int i = 0; i < DIN; i++) o = fmaf(ao[i], Wo[i*DIN + tid], o);
        out[(size_t)q*DIN + tid] = o;
    }
}

extern "C" void kernel_launch(void* const* d_in, const int* in_sizes, int n_in,
                              void* d_out, int out_size, void* d_ws, size_t ws_size,
                              hipStream_t stream) {
    const float* x    = (const float*)d_in[0];
    const float* bias = (const float*)d_in[1];
    const float* lnw  = (const float*)d_in[2];
    const float* lnb  = (const float*)d_in[3];
    const float* lbw  = (const float*)d_in[4];
    const float* lbb  = (const float*)d_in[5];
    const float* Wq   = (const float*)d_in[6];
    const float* Wk   = (const float*)d_in[7];
    const float* Wv   = (const float*)d_in[8];
    const float* Wb   = (const float*)d_in[9];
    const float* Wg   = (const float*)d_in[10];
    const float* bg   = (const float*)d_in[11];
    const float* Wo   = (const float*)d_in[12];
    const float* bo   = (const float*)d_in[13];

    float* ws = (float*)d_ws;
    float* qb = ws + OFF_QB;
    float* kT = ws + OFF_KT;
    float* vb = ws + OFF_VB;
    float* gb = ws + OFF_GB;
    float* W2 = ws + OFF_W2;
    float* SC = ws + OFF_SC;

    projsetup_kernel<<<193, 256, 0, stream>>>(x, lnw, lnb, Wq, Wk, Wv, Wg, bg,
                                              lbw, lbb, Wb, qb, kT, vb, gb, W2, SC);
    mega_kernel<<<LQ, 256, 0, stream>>>(bias, W2, SC, qb, kT, vb, gb, Wo, bo, (float*)d_out);
}

// Round 12
// 173.822 us; speedup vs baseline: 1.3291x; 1.1737x over previous
//
#include <hip/hip_runtime.h>

#define LQ 768
#define DIN 256
#define DB 128
#define NH 8
#define DH 32

// ws float offsets
#define OFF_QB 0
#define OFF_KT (LQ*DIN)          // kT[DIN][LQ]  transposed, pre-scaled K
#define OFF_VB (2*LQ*DIN)
#define OFF_GB (3*LQ*DIN)
#define OFF_W2 (4*LQ*DIN)
#define OFF_SC (OFF_W2 + DB*NH)

__device__ __forceinline__ void gload_lds16(const void* g, void* l) {
    __builtin_amdgcn_global_load_lds(
        (__attribute__((address_space(1))) const void*)g,
        (__attribute__((address_space(3))) void*)l,
        16, 0, 0);
}

// ---------------------------------------------------------------------------
// K1: proj (blocks 0..191, 4 rows each; K written transposed+scaled) +
//     setup (block 192: W2/S/C fold of the bias layernorm).
// ---------------------------------------------------------------------------
__global__ __launch_bounds__(256) void projsetup_kernel(
    const float* __restrict__ x, const float* __restrict__ lnw, const float* __restrict__ lnb,
    const float* __restrict__ Wq, const float* __restrict__ Wk, const float* __restrict__ Wv,
    const float* __restrict__ Wg, const float* __restrict__ bg,
    const float* __restrict__ lbw, const float* __restrict__ lbb, const float* __restrict__ Wb,
    float* __restrict__ qb, float* __restrict__ kT, float* __restrict__ vb, float* __restrict__ gb,
    float* __restrict__ W2, float* __restrict__ SC)
{
    const int tid = threadIdx.x;

    if (blockIdx.x == 192) {            // ---- setup ----
        if (tid < 128) {
            const int d = tid, lane = d & 63, wv = d >> 6;
            float w = lbw[d], b = lbb[d];
            float pS[NH], pC[NH];
            #pragma unroll
            for (int h = 0; h < NH; h++) {
                float wb = Wb[d*NH + h];
                float w2 = w * wb;
                W2[d*NH + h] = w2;
                pS[h] = w2;
                pC[h] = b * wb;
            }
            #pragma unroll
            for (int m = 1; m <= 32; m <<= 1) {
                #pragma unroll
                for (int h = 0; h < NH; h++) { pS[h] += __shfl_xor(pS[h], m); pC[h] += __shfl_xor(pC[h], m); }
            }
            __shared__ float red[2][16];
            if (lane == 0) {
                #pragma unroll
                for (int h = 0; h < NH; h++) { red[wv][h] = pS[h]; red[wv][NH+h] = pC[h]; }
            }
            __syncthreads();
            if (d < 16) SC[d] = red[0][d] + red[1][d];
        }
        return;
    }

    // ---- proj: 4 rows per block ----
    const int lane = tid & 63, rr = tid >> 6;
    const int row = blockIdx.x * 4 + rr;
    __shared__ float xn[4][DIN];

    float4 xv = ((const float4*)x)[row * (DIN/4) + lane];
    float s  = xv.x + xv.y + xv.z + xv.w;
    float ss = xv.x*xv.x + xv.y*xv.y + xv.z*xv.z + xv.w*xv.w;
    #pragma unroll
    for (int m = 1; m <= 32; m <<= 1) { s += __shfl_xor(s, m); ss += __shfl_xor(ss, m); }
    float mu  = s * (1.0f/DIN);
    float inv = rsqrtf(ss * (1.0f/DIN) - mu*mu + 1e-5f);
    float4 wv4 = ((const float4*)lnw)[lane];
    float4 bv4 = ((const float4*)lnb)[lane];
    float4 r4;
    r4.x = (xv.x - mu)*inv*wv4.x + bv4.x;
    r4.y = (xv.y - mu)*inv*wv4.y + bv4.y;
    r4.z = (xv.z - mu)*inv*wv4.z + bv4.z;
    r4.w = (xv.w - mu)*inv*wv4.w + bv4.w;
    *((float4*)&xn[rr][lane*4]) = r4;
    __syncthreads();

    const int col = tid;
    float aq[4] = {0,0,0,0}, ak[4] = {0,0,0,0}, av[4] = {0,0,0,0}, ag[4] = {0,0,0,0};
    for (int i4 = 0; i4 < DIN/4; i4++) {
        float4 x0 = *((const float4*)&xn[0][i4*4]);
        float4 x1 = *((const float4*)&xn[1][i4*4]);
        float4 x2 = *((const float4*)&xn[2][i4*4]);
        float4 x3 = *((const float4*)&xn[3][i4*4]);
        const float* p0 = (const float*)&x0;
        const float* p1 = (const float*)&x1;
        const float* p2 = (const float*)&x2;
        const float* p3 = (const float*)&x3;
        #pragma unroll
        for (int e = 0; e < 4; e++) {
            const int i = i4*4 + e;
            float wq = Wq[i*DIN + col], wk = Wk[i*DIN + col];
            float wvv = Wv[i*DIN + col], wg = Wg[i*DIN + col];
            aq[0] = fmaf(p0[e], wq, aq[0]); aq[1] = fmaf(p1[e], wq, aq[1]);
            aq[2] = fmaf(p2[e], wq, aq[2]); aq[3] = fmaf(p3[e], wq, aq[3]);
            ak[0] = fmaf(p0[e], wk, ak[0]); ak[1] = fmaf(p1[e], wk, ak[1]);
            ak[2] = fmaf(p2[e], wk, ak[2]); ak[3] = fmaf(p3[e], wk, ak[3]);
            av[0] = fmaf(p0[e], wvv, av[0]); av[1] = fmaf(p1[e], wvv, av[1]);
            av[2] = fmaf(p2[e], wvv, av[2]); av[3] = fmaf(p3[e], wvv, av[3]);
            ag[0] = fmaf(p0[e], wg, ag[0]); ag[1] = fmaf(p1[e], wg, ag[1]);
            ag[2] = fmaf(p2[e], wg, ag[2]); ag[3] = fmaf(p3[e], wg, ag[3]);
        }
    }
    const float kscale = 0.17677669529663687f;  // 1/sqrt(DH)
    float bgv = bg[col];
    #pragma unroll
    for (int r = 0; r < 4; r++) {
        const int orow = blockIdx.x*4 + r;
        qb[orow*DIN + col] = aq[r];
        vb[orow*DIN + col] = av[r];
        gb[orow*DIN + col] = 1.0f/(1.0f + __expf(-(ag[r] + bgv)));
    }
    *((float4*)&kT[col*LQ + blockIdx.x*4]) =
        make_float4(ak[0]*kscale, ak[1]*kscale, ak[2]*kscale, ak[3]*kscale);
}

// ---------------------------------------------------------------------------
// K2: mega per-q kernel, column-scan + gload_lds edition.
// Per wave: 192 keys = 3 key-blocks of 64; each key-block streamed as 8
// d-stages of 64 keys x 16 dims (4KB tile, 4x gload_lds, double-buffered).
// Lane = key: full LN stats + 8-head projection accumulate PRIVATELY
// (zero shuffles, zero W2 LDS traffic; W2 rows are wave-uniform loads).
// Swizzle (both-sides, rule #21): slot g of key k holds dim-group
// (g-(k>>1))&3, via pre-swizzled per-lane GLOBAL source; read addr
// k*64 + (((k>>1)+j)&3)*16 covers all 32 banks (8 words/bank = ideal)
// and delivers dim-group j uniformly -> W2 operand is scalar.
// Steady-state s_waitcnt vmcnt(4); robust even if W2 reads compile to VMEM
// (in-order retirement). DS cost per stage: 4 b128 (vs R11's 66 DS ops).
// ---------------------------------------------------------------------------
__global__ __launch_bounds__(256, 2) void mega_kernel(
    const float* __restrict__ bias, const float* __restrict__ W2g,
    const float* __restrict__ SCg, const float* __restrict__ qbuf,
    const float* __restrict__ kT, const float* __restrict__ vbuf,
    const float* __restrict__ gbuf, const float* __restrict__ Wo,
    const float* __restrict__ bo, float* __restrict__ out)
{
    __shared__ float tiles[4][2][1024];  // [wave][buf][4KB]
    __shared__ float pT[NH][776];
    __shared__ float ao[DIN];
    __shared__ float isum[NH];

    const int tid  = threadIdx.x;
    const int q    = blockIdx.x;
    const int w    = tid >> 6;
    const int lane = tid & 63;           // = key within 64-key block

    const char* gq = (const char*)bias + ((size_t)q*LQ + w*192) * (DB*4);

    // staging source offsets: lane l' writes LDS A = c*1024+l'*16;
    // key(A) = c*16 + (l'>>2); slot(A) = l'&3; content dim-group
    // gc = (slot - (key>>1)) & 3 = ((l'&3) - ((l'>>3)&3)) & 3  (c-indep).
    const int keyc = lane >> 2;
    const int rot  = ((lane & 3) - ((lane >> 3) & 3)) & 3;
    const int soff = keyc*512 + rot*16;

    #define STAGE(t2, b) {                                                   \
        const char* gt = gq + ((t2) >> 3)*32768 + ((t2) & 7)*64;             \
        char* lb = (char*)&tiles[w][b][0];                                   \
        _Pragma("unroll")                                                    \
        for (int c = 0; c < 4; c++)                                          \
            gload_lds16(gt + c*8192 + soff, lb + c*1024);                    \
    }

    // prologue: stage t=0,1 (fly during the qk prologue below)
    STAGE(0, 0);
    STAGE(1, 1);

    // qk prologue: 192 threads, 4 keys each, all 8 heads -> pT
    if (tid < 192) {
        float acc[4][NH];
        #pragma unroll
        for (int e = 0; e < 4; e++)
            #pragma unroll
            for (int h = 0; h < NH; h++) acc[e][h] = 0.f;
        const float* qp = qbuf + (size_t)q*DIN;          // uniform
        #pragma unroll
        for (int h = 0; h < NH; h++) {
            #pragma unroll
            for (int dd = 0; dd < DH; dd++) {
                const int d = h*DH + dd;
                float4 kv = *(const float4*)(kT + (size_t)d*LQ + tid*4);
                float qa = qp[d];
                acc[0][h] = fmaf(qa, kv.x, acc[0][h]);
                acc[1][h] = fmaf(qa, kv.y, acc[1][h]);
                acc[2][h] = fmaf(qa, kv.z, acc[2][h]);
                acc[3][h] = fmaf(qa, kv.w, acc[3][h]);
            }
        }
        #pragma unroll
        for (int h = 0; h < NH; h++)
            *(float4*)&pT[h][tid*4] = make_float4(acc[0][h], acc[1][h], acc[2][h], acc[3][h]);
    }

    asm volatile("s_waitcnt lgkmcnt(0)" ::: "memory");
    __builtin_amdgcn_s_barrier();

    float Sh[NH], Ch[NH];
    #pragma unroll
    for (int h = 0; h < NH; h++) { Sh[h] = SCg[h]; Ch[h] = SCg[NH + h]; }

    // scan read base pieces
    const int a0  = lane * 64;
    const int rl  = (lane >> 1) & 3;

    float s = 0.f, ss = 0.f;
    float acc[NH] = {0,0,0,0,0,0,0,0};

    #pragma unroll 1
    for (int t = 0; t < 24; t++) {
        if (t < 23) asm volatile("s_waitcnt vmcnt(4)" ::: "memory");
        else        asm volatile("s_waitcnt vmcnt(0)" ::: "memory");

        // ---- scan stage t (16 dims of this wave's 64-key block) ----
        {
            const char* tb = (const char*)&tiles[w][t & 1][0];
            const int ds = t & 7;
            const float* wr0 = W2g + ds*16*NH;           // uniform base
            #pragma unroll
            for (int j = 0; j < 4; j++) {
                float4 bv = *(const float4*)(tb + a0 + (((rl + j) & 3) << 4));
                const float* wr = wr0 + j*4*NH;
                #pragma unroll
                for (int e = 0; e < 4; e++) {
                    float xv = (&bv.x)[e];
                    s += xv; ss = fmaf(xv, xv, ss);
                    #pragma unroll
                    for (int h = 0; h < NH; h++)
                        acc[h] = fmaf(xv, wr[e*NH + h], acc[h]);
                }
            }
        }
        asm volatile("s_waitcnt lgkmcnt(0)" ::: "memory");  // WAR: reads done
        if (t + 2 < 24) STAGE(t + 2, t & 1);

        if ((t & 7) == 7) {          // ---- finalize this 64-key block ----
            float mu  = s * (1.0f/DB);
            float inv = rsqrtf(ss * (1.0f/DB) - mu*mu + 1e-5f);
            const int k = w*192 + (t >> 3)*64 + lane;
            #pragma unroll
            for (int h = 0; h < NH; h++)
                pT[h][k] += fmaf(inv, fmaf(-mu, Sh[h], acc[h]), Ch[h]);
            s = 0.f; ss = 0.f;
            #pragma unroll
            for (int h = 0; h < NH; h++) acc[h] = 0.f;
        }
    }
    #undef STAGE

    asm volatile("s_waitcnt lgkmcnt(0)" ::: "memory");
    __builtin_amdgcn_s_barrier();

    // ---- softmax over keys per head ----
    {
        const int h = tid >> 5, l = tid & 31;
        float m = -1e30f;
        for (int i = l; i < LQ; i += 32) m = fmaxf(m, pT[h][i]);
        #pragma unroll
        for (int mm = 1; mm <= 16; mm <<= 1) m = fmaxf(m, __shfl_xor(m, mm));
        float sum = 0.f;
        for (int i = l; i < LQ; i += 32) {
            float e = __expf(pT[h][i] - m);
            pT[h][i] = e;
            sum += e;
        }
        #pragma unroll
        for (int mm = 1; mm <= 16; mm <<= 1) sum += __shfl_xor(sum, mm);
        if (l == 0) isum[h] = 1.0f / sum;
    }
    __syncthreads();

    // ---- PV + gate ----
    {
        const int h = tid >> 5, d = tid & 31;
        const float* vp = vbuf + h*DH + d;
        float a = 0.f;
        for (int k4 = 0; k4 < LQ/4; k4++) {
            float4 p = *(const float4*)&pT[h][k4*4];     // broadcast
            a = fmaf(p.x, vp[(size_t)(k4*4+0)*DIN], a);
            a = fmaf(p.y, vp[(size_t)(k4*4+1)*DIN], a);
            a = fmaf(p.z, vp[(size_t)(k4*4+2)*DIN], a);
            a = fmaf(p.w, vp[(size_t)(k4*4+3)*DIN], a);
        }
        ao[tid] = a * isum[h] * gbuf[(size_t)q*DIN + tid];
    }
    __syncthreads();

    // ---- output projection ----
    {
        float o = bo[tid];
        for (int i = 0; i < DIN; i++) o = fmaf(ao[i], Wo[i*DIN + tid], o);
        out[(size_t)q*DIN + tid] = o;
    }
}

extern "C" void kernel_launch(void* const* d_in, const int* in_sizes, int n_in,
                              void* d_out, int out_size, void* d_ws, size_t ws_size,
                              hipStream_t stream) {
    const float* x    = (const float*)d_in[0];
    const float* bias = (const float*)d_in[1];
    const float* lnw  = (const float*)d_in[2];
    const float* lnb  = (const float*)d_in[3];
    const float* lbw  = (const float*)d_in[4];
    const float* lbb  = (const float*)d_in[5];
    const float* Wq   = (const float*)d_in[6];
    const float* Wk   = (const float*)d_in[7];
    const float* Wv   = (const float*)d_in[8];
    const float* Wb   = (const float*)d_in[9];
    const float* Wg   = (const float*)d_in[10];
    const float* bg   = (const float*)d_in[11];
    const float* Wo   = (const float*)d_in[12];
    const float* bo   = (const float*)d_in[13];

    float* ws = (float*)d_ws;
    float* qb = ws + OFF_QB;
    float* kT = ws + OFF_KT;
    float* vb = ws + OFF_VB;
    float* gb = ws + OFF_GB;
    float* W2 = ws + OFF_W2;
    float* SC = ws + OFF_SC;

    projsetup_kernel<<<193, 256, 0, stream>>>(x, lnw, lnb, Wq, Wk, Wv, Wg, bg,
                                              lbw, lbb, Wb, qb, kT, vb, gb, W2, SC);
    mega_kernel<<<LQ, 256, 0, stream>>>(bias, W2, SC, qb, kT, vb, gb, Wo, bo, (float*)d_out);
}

// Round 13
// 156.502 us; speedup vs baseline: 1.4762x; 1.1107x over previous
//
#include <hip/hip_runtime.h>

#define LQ 768
#define DIN 256
#define DB 128
#define NH 8
#define DH 32

// ws float offsets
#define OFF_QB 0
#define OFF_KT (LQ*DIN)          // kT[DIN][LQ]  transposed, pre-scaled K
#define OFF_VB (2*LQ*DIN)
#define OFF_GB (3*LQ*DIN)
#define OFF_W2 (4*LQ*DIN)
#define OFF_SC (OFF_W2 + DB*NH)
#define OFF_LG (OFF_SC + 16)     // logits[q][k][h] (bias-LN part only), 18.9 MB

__device__ __forceinline__ void gload_lds16(const void* g, void* l) {
    __builtin_amdgcn_global_load_lds(
        (__attribute__((address_space(1))) const void*)g,
        (__attribute__((address_space(3))) void*)l,
        16, 0, 0);
}

// ---------------------------------------------------------------------------
// K1: proj (blocks 0..191, 4 rows each; K written transposed+scaled) +
//     setup (block 192: W2/S/C fold of the bias layernorm).
// ---------------------------------------------------------------------------
__global__ __launch_bounds__(256) void projsetup_kernel(
    const float* __restrict__ x, const float* __restrict__ lnw, const float* __restrict__ lnb,
    const float* __restrict__ Wq, const float* __restrict__ Wk, const float* __restrict__ Wv,
    const float* __restrict__ Wg, const float* __restrict__ bg,
    const float* __restrict__ lbw, const float* __restrict__ lbb, const float* __restrict__ Wb,
    float* __restrict__ qb, float* __restrict__ kT, float* __restrict__ vb, float* __restrict__ gb,
    float* __restrict__ W2, float* __restrict__ SC)
{
    const int tid = threadIdx.x;

    if (blockIdx.x == 192) {            // ---- setup ----
        if (tid < 128) {
            const int d = tid, lane = d & 63, wv = d >> 6;
            float w = lbw[d], b = lbb[d];
            float pS[NH], pC[NH];
            #pragma unroll
            for (int h = 0; h < NH; h++) {
                float wb = Wb[d*NH + h];
                float w2 = w * wb;
                W2[d*NH + h] = w2;
                pS[h] = w2;
                pC[h] = b * wb;
            }
            #pragma unroll
            for (int m = 1; m <= 32; m <<= 1) {
                #pragma unroll
                for (int h = 0; h < NH; h++) { pS[h] += __shfl_xor(pS[h], m); pC[h] += __shfl_xor(pC[h], m); }
            }
            __shared__ float red[2][16];
            if (lane == 0) {
                #pragma unroll
                for (int h = 0; h < NH; h++) { red[wv][h] = pS[h]; red[wv][NH+h] = pC[h]; }
            }
            __syncthreads();
            if (d < 16) SC[d] = red[0][d] + red[1][d];
        }
        return;
    }

    // ---- proj: 4 rows per block ----
    const int lane = tid & 63, rr = tid >> 6;
    const int row = blockIdx.x * 4 + rr;
    __shared__ float xn[4][DIN];

    float4 xv = ((const float4*)x)[row * (DIN/4) + lane];
    float s  = xv.x + xv.y + xv.z + xv.w;
    float ss = xv.x*xv.x + xv.y*xv.y + xv.z*xv.z + xv.w*xv.w;
    #pragma unroll
    for (int m = 1; m <= 32; m <<= 1) { s += __shfl_xor(s, m); ss += __shfl_xor(ss, m); }
    float mu  = s * (1.0f/DIN);
    float inv = rsqrtf(ss * (1.0f/DIN) - mu*mu + 1e-5f);
    float4 wv4 = ((const float4*)lnw)[lane];
    float4 bv4 = ((const float4*)lnb)[lane];
    float4 r4;
    r4.x = (xv.x - mu)*inv*wv4.x + bv4.x;
    r4.y = (xv.y - mu)*inv*wv4.y + bv4.y;
    r4.z = (xv.z - mu)*inv*wv4.z + bv4.z;
    r4.w = (xv.w - mu)*inv*wv4.w + bv4.w;
    *((float4*)&xn[rr][lane*4]) = r4;
    __syncthreads();

    const int col = tid;
    float aq[4] = {0,0,0,0}, ak[4] = {0,0,0,0}, av[4] = {0,0,0,0}, ag[4] = {0,0,0,0};
    for (int i4 = 0; i4 < DIN/4; i4++) {
        float4 x0 = *((const float4*)&xn[0][i4*4]);
        float4 x1 = *((const float4*)&xn[1][i4*4]);
        float4 x2 = *((const float4*)&xn[2][i4*4]);
        float4 x3 = *((const float4*)&xn[3][i4*4]);
        const float* p0 = (const float*)&x0;
        const float* p1 = (const float*)&x1;
        const float* p2 = (const float*)&x2;
        const float* p3 = (const float*)&x3;
        #pragma unroll
        for (int e = 0; e < 4; e++) {
            const int i = i4*4 + e;
            float wq = Wq[i*DIN + col], wk = Wk[i*DIN + col];
            float wvv = Wv[i*DIN + col], wg = Wg[i*DIN + col];
            aq[0] = fmaf(p0[e], wq, aq[0]); aq[1] = fmaf(p1[e], wq, aq[1]);
            aq[2] = fmaf(p2[e], wq, aq[2]); aq[3] = fmaf(p3[e], wq, aq[3]);
            ak[0] = fmaf(p0[e], wk, ak[0]); ak[1] = fmaf(p1[e], wk, ak[1]);
            ak[2] = fmaf(p2[e], wk, ak[2]); ak[3] = fmaf(p3[e], wk, ak[3]);
            av[0] = fmaf(p0[e], wvv, av[0]); av[1] = fmaf(p1[e], wvv, av[1]);
            av[2] = fmaf(p2[e], wvv, av[2]); av[3] = fmaf(p3[e], wvv, av[3]);
            ag[0] = fmaf(p0[e], wg, ag[0]); ag[1] = fmaf(p1[e], wg, ag[1]);
            ag[2] = fmaf(p2[e], wg, ag[2]); ag[3] = fmaf(p3[e], wg, ag[3]);
        }
    }
    const float kscale = 0.17677669529663687f;  // 1/sqrt(DH)
    float bgv = bg[col];
    #pragma unroll
    for (int r = 0; r < 4; r++) {
        const int orow = blockIdx.x*4 + r;
        qb[orow*DIN + col] = aq[r];
        vb[orow*DIN + col] = av[r];
        gb[orow*DIN + col] = 1.0f/(1.0f + __expf(-(ag[r] + bgv)));
    }
    *((float4*)&kT[col*LQ + blockIdx.x*4]) =
        make_float4(ak[0]*kscale, ak[1]*kscale, ak[2]*kscale, ak[3]*kscale);
}

// ---------------------------------------------------------------------------
// K2: bias streamer, column-scan + gload_lds, 4-deep, high-occupancy.
// Grid (2, 768), block 128 (2 waves). LDS = 32KB -> 5 blocks/CU = 10 waves.
// Wave owns 192 keys = 3 key-blocks of 64; each key-block = 8 d-stages of
// 64 keys x 16 dims (4KB tile, 4x gload_lds). 4-buffer rotation, steady
// vmcnt(12) (3 tiles in flight), tail 8/4/0. Lane = key: private LN stats +
// 8-head projection (zero shuffles, zero W2-LDS). Logits kept in registers
// (kb compile-time) and stored after the final vmcnt(0) -> the vmcnt ledger
// contains ONLY gload_lds ops. Swizzle identical to R12 (refcheck-proven).
// ---------------------------------------------------------------------------
__global__ __launch_bounds__(128) void bias13_kernel(
    const float* __restrict__ bias, const float* __restrict__ W2g,
    const float* __restrict__ SCg, float* __restrict__ logits)
{
    __shared__ float tiles[2][4][1024];   // [wave][buf][4KB] = 32KB
    const int tid  = threadIdx.x;
    const int w    = tid >> 6;
    const int lane = tid & 63;            // = key within 64-key block
    const int q    = blockIdx.y;
    const int keybase = blockIdx.x * 384 + w * 192;

    const char* gq = (const char*)bias + ((size_t)q*LQ + keybase) * (DB*4);
    char* const lb0 = (char*)&tiles[w][0][0];

    // staging source offset (R12 involution): lane l' writes LDS
    // A = c*1024+l'*16; content dim-group rot = ((l'&3)-((l'>>3)&3))&3.
    const int keyc = lane >> 2;
    const int rot  = ((lane & 3) - ((lane >> 3) & 3)) & 3;
    const int soff = keyc*512 + rot*16;

    #define STAGE(T) {                                                       \
        const char* gt = gq + ((T) >> 3)*32768 + ((T) & 7)*64;               \
        char* lb = lb0 + (((T) & 3) << 12);                                  \
        _Pragma("unroll")                                                    \
        for (int c = 0; c < 4; c++)                                          \
            gload_lds16(gt + c*8192 + soff, lb + c*1024);                    \
    }

    // prologue: 4 tiles in flight
    STAGE(0); STAGE(1); STAGE(2); STAGE(3);

    float Sh[NH], Ch[NH];
    #pragma unroll
    for (int h = 0; h < NH; h++) { Sh[h] = SCg[h]; Ch[h] = SCg[NH + h]; }

    const int a0 = lane * 64;
    const int rl = (lane >> 1) & 3;

    float lo[3][NH];

    #pragma unroll
    for (int kb = 0; kb < 3; kb++) {
        float s = 0.f, ss = 0.f;
        float acc[NH] = {0,0,0,0,0,0,0,0};
        #pragma unroll 1
        for (int sd = 0; sd < 8; sd++) {
            const int T = kb*8 + sd;
            if (T <= 20)      asm volatile("s_waitcnt vmcnt(12)" ::: "memory");
            else if (T == 21) asm volatile("s_waitcnt vmcnt(8)"  ::: "memory");
            else if (T == 22) asm volatile("s_waitcnt vmcnt(4)"  ::: "memory");
            else              asm volatile("s_waitcnt vmcnt(0)"  ::: "memory");

            const char* tb = lb0 + ((T & 3) << 12);
            const float* wr0 = W2g + sd*16*NH;            // wave-uniform
            #pragma unroll
            for (int j = 0; j < 4; j++) {
                float4 bv = *(const float4*)(tb + a0 + (((rl + j) & 3) << 4));
                const float* wr = wr0 + j*4*NH;
                #pragma unroll
                for (int e = 0; e < 4; e++) {
                    float xv = (&bv.x)[e];
                    s += xv; ss = fmaf(xv, xv, ss);
                    #pragma unroll
                    for (int h = 0; h < NH; h++)
                        acc[h] = fmaf(xv, wr[e*NH + h], acc[h]);
                }
            }
            asm volatile("s_waitcnt lgkmcnt(0)" ::: "memory");  // WAR: reads done
            if (T + 4 < 24) STAGE(T + 4);
        }
        float mu  = s * (1.0f/DB);
        float inv = rsqrtf(ss * (1.0f/DB) - mu*mu + 1e-5f);
        #pragma unroll
        for (int h = 0; h < NH; h++)
            lo[kb][h] = fmaf(inv, fmaf(-mu, Sh[h], acc[h]), Ch[h]);
    }
    #undef STAGE

    // all DMA retired (vmcnt(0) above) -> store logits, coalesced
    #pragma unroll
    for (int kb = 0; kb < 3; kb++) {
        float4* dst = (float4*)(logits + ((size_t)q*LQ + keybase + kb*64 + lane)*NH);
        dst[0] = make_float4(lo[kb][0], lo[kb][1], lo[kb][2], lo[kb][3]);
        dst[1] = make_float4(lo[kb][4], lo[kb][5], lo[kb][6], lo[kb][7]);
    }
}

// ---------------------------------------------------------------------------
// K3: attn tail (R5-proven): logits -> pT transposed, add qk from kT,
// softmax (contiguous float4 rows), PV, gate, Wo. 2 q-rows/block, grid 384.
// ---------------------------------------------------------------------------
__global__ __launch_bounds__(256) void attn_kernel(
    const float* __restrict__ logits, const float* __restrict__ qbuf,
    const float* __restrict__ kT, const float* __restrict__ vbuf,
    const float* __restrict__ gb, const float* __restrict__ Wo,
    const float* __restrict__ bo, float* __restrict__ out)
{
    const int tid = threadIdx.x;
    const int q0 = blockIdx.x * 2;
    __shared__ float pT[2][NH][776];
    __shared__ float ao[2][DIN];
    __shared__ float isum[2][NH];

    #pragma unroll
    for (int r = 0; r < 2; r++) {
        const float4* rp = (const float4*)(logits + (size_t)(q0 + r)*LQ*NH);
        #pragma unroll
        for (int ii = 0; ii < 6; ii++) {
            int jj = ii*256 + tid;
            float4 t = rp[jj];
            int k = jj >> 1, h0 = (jj & 1) << 2;
            pT[r][h0+0][k] = t.x; pT[r][h0+1][k] = t.y;
            pT[r][h0+2][k] = t.z; pT[r][h0+3][k] = t.w;
        }
    }
    __syncthreads();

    if (tid < 192) {
        const float* q0p = qbuf + (size_t)q0*DIN;
        const float* q1p = q0p + DIN;
        #pragma unroll
        for (int h = 0; h < NH; h++) {
            float a00=0,a01=0,a02=0,a03=0, a10=0,a11=0,a12=0,a13=0;
            #pragma unroll
            for (int dd = 0; dd < DH; dd++) {
                const int d = h*DH + dd;
                float4 kv = *(const float4*)(kT + (size_t)d*LQ + tid*4);
                float qa = q0p[d], qc = q1p[d];
                a00 = fmaf(qa, kv.x, a00); a01 = fmaf(qa, kv.y, a01);
                a02 = fmaf(qa, kv.z, a02); a03 = fmaf(qa, kv.w, a03);
                a10 = fmaf(qc, kv.x, a10); a11 = fmaf(qc, kv.y, a11);
                a12 = fmaf(qc, kv.z, a12); a13 = fmaf(qc, kv.w, a13);
            }
            float4 p0 = *(float4*)&pT[0][h][tid*4];
            p0.x += a00; p0.y += a01; p0.z += a02; p0.w += a03;
            *(float4*)&pT[0][h][tid*4] = p0;
            float4 p1 = *(float4*)&pT[1][h][tid*4];
            p1.x += a10; p1.y += a11; p1.z += a12; p1.w += a13;
            *(float4*)&pT[1][h][tid*4] = p1;
        }
    }
    __syncthreads();

    {
        const int r = tid >> 7, h = (tid >> 4) & 7, l = tid & 15;
        float4* row = (float4*)&pT[r][h][0];
        float m = -1e30f;
        for (int i = l; i < 192; i += 16) {
            float4 v = row[i];
            m = fmaxf(m, fmaxf(fmaxf(v.x, v.y), fmaxf(v.z, v.w)));
        }
        #pragma unroll
        for (int mm = 1; mm <= 8; mm <<= 1) m = fmaxf(m, __shfl_xor(m, mm));
        float sum = 0.f;
        for (int i = l; i < 192; i += 16) {
            float4 v = row[i];
            v.x = __expf(v.x - m); v.y = __expf(v.y - m);
            v.z = __expf(v.z - m); v.w = __expf(v.w - m);
            sum += v.x + v.y + v.z + v.w;
            row[i] = v;
        }
        #pragma unroll
        for (int mm = 1; mm <= 8; mm <<= 1) sum += __shfl_xor(sum, mm);
        if (l == 0) isum[r][h] = 1.0f / sum;
    }
    __syncthreads();

    {
        const int h = tid >> 5, d = tid & 31;
        const float* vp = vbuf + h*DH + d;
        const float4* p0r = (const float4*)&pT[0][h][0];
        const float4* p1r = (const float4*)&pT[1][h][0];
        float a0 = 0.f, a1 = 0.f;
        for (int k4 = 0; k4 < 192; k4++) {
            float4 p0 = p0r[k4], p1 = p1r[k4];
            float v0 = vp[(size_t)(k4*4+0)*DIN];
            float v1 = vp[(size_t)(k4*4+1)*DIN];
            float v2 = vp[(size_t)(k4*4+2)*DIN];
            float v3 = vp[(size_t)(k4*4+3)*DIN];
            a0 = fmaf(p0.x, v0, a0); a0 = fmaf(p0.y, v1, a0);
            a0 = fmaf(p0.z, v2, a0); a0 = fmaf(p0.w, v3, a0);
            a1 = fmaf(p1.x, v0, a1); a1 = fmaf(p1.y, v1, a1);
            a1 = fmaf(p1.z, v2, a1); a1 = fmaf(p1.w, v3, a1);
        }
        ao[0][tid] = a0 * isum[0][h] * gb[(q0+0)*DIN + tid];
        ao[1][tid] = a1 * isum[1][h] * gb[(q0+1)*DIN + tid];
    }
    __syncthreads();

    {
        const int col = tid;
        float o0 = bo[col], o1 = o0;
        for (int i = 0; i < DIN; i++) {
            float wv = Wo[i*DIN + col];
            o0 = fmaf(ao[0][i], wv, o0);
            o1 = fmaf(ao[1][i], wv, o1);
        }
        out[(q0+0)*DIN + col] = o0;
        out[(q0+1)*DIN + col] = o1;
    }
}

extern "C" void kernel_launch(void* const* d_in, const int* in_sizes, int n_in,
                              void* d_out, int out_size, void* d_ws, size_t ws_size,
                              hipStream_t stream) {
    const float* x    = (const float*)d_in[0];
    const float* bias = (const float*)d_in[1];
    const float* lnw  = (const float*)d_in[2];
    const float* lnb  = (const float*)d_in[3];
    const float* lbw  = (const float*)d_in[4];
    const float* lbb  = (const float*)d_in[5];
    const float* Wq   = (const float*)d_in[6];
    const float* Wk   = (const float*)d_in[7];
    const float* Wv   = (const float*)d_in[8];
    const float* Wb   = (const float*)d_in[9];
    const float* Wg   = (const float*)d_in[10];
    const float* bg   = (const float*)d_in[11];
    const float* Wo   = (const float*)d_in[12];
    const float* bo   = (const float*)d_in[13];

    float* ws = (float*)d_ws;
    float* qb = ws + OFF_QB;
    float* kT = ws + OFF_KT;
    float* vb = ws + OFF_VB;
    float* gb = ws + OFF_GB;
    float* W2 = ws + OFF_W2;
    float* SC = ws + OFF_SC;
    float* lg = ws + OFF_LG;

    projsetup_kernel<<<193, 256, 0, stream>>>(x, lnw, lnb, Wq, Wk, Wv, Wg, bg,
                                              lbw, lbb, Wb, qb, kT, vb, gb, W2, SC);
    bias13_kernel<<<dim3(2, LQ), 128, 0, stream>>>(bias, W2, SC, lg);
    attn_kernel<<<LQ/2, 256, 0, stream>>>(lg, qb, kT, vb, gb, Wo, bo, (float*)d_out);
}